// Round 1
// baseline (232.086 us; speedup 1.0000x reference)
//
#include <hip/hip_runtime.h>

// Bilinear resample: inputs (B,S,S,C) fp32, offsets (B,S,S,2) fp32 -> out (B,S,S,C)
// B=16, S=128, C=128. Memory-bound gather with near-identity sampling grid.

constexpr int S = 128;
constexpr int CVEC = 32;          // C/4 = 128/4 float4 groups per pixel
constexpr int PIX_PER_BLOCK = 8;  // 256 threads / 32 threads-per-pixel

__global__ __launch_bounds__(256) void resample_kernel(
    const float* __restrict__ offsets,   // (B, S, S, 2)
    const float4* __restrict__ inputs4,  // (B, S, S, C/4) as float4
    float4* __restrict__ out4)           // (B, S, S, C/4)
{
    const int tid      = threadIdx.x;
    const int lane_c   = tid & 31;       // channel-group index (0..31)
    const int pix_blk  = tid >> 5;       // pixel within block (0..7)
    const int pix      = blockIdx.x * PIX_PER_BLOCK + pix_blk;  // (b*S + i)*S + j

    const int j   = pix & (S - 1);
    const int rem = pix >> 7;            // b*S + i
    const int i   = rem & (S - 1);
    const int b   = rem >> 7;

    // Per-pixel coords & weights (computed redundantly by the 32 lanes of this pixel)
    const float oy = offsets[pix * 2 + 0];
    const float ox = offsets[pix * 2 + 1];
    float y = fminf(fmaxf((float)i + oy, 0.0f), (float)(S - 1));
    float x = fminf(fmaxf((float)j + ox, 0.0f), (float)(S - 1));

    const float y0f = floorf(y);
    const float x0f = floorf(x);
    const int y0 = (int)y0f;
    const int x0 = (int)x0f;
    const int y1 = (int)ceilf(y);        // == y0 when y is integral (matches reference)
    const int x1 = (int)ceilf(x);
    const float fy = y - y0f;            // row fraction  (reference "fx")
    const float fx = x - x0f;            // col fraction  (reference "fy")

    // inputs4 index for (b, yy, xx, lane_c): ((b*S + yy)*S + xx)*32 + lane_c
    const int base = (b * S * S) * CVEC + lane_c;
    const int r0 = base + y0 * (S * CVEC);
    const int r1 = base + y1 * (S * CVEC);

    const float4 v00 = inputs4[r0 + x0 * CVEC];
    const float4 v01 = inputs4[r0 + x1 * CVEC];
    const float4 v10 = inputs4[r1 + x0 * CVEC];
    const float4 v11 = inputs4[r1 + x1 * CVEC];

    // Match reference order: lerp along x (fy in ref), then along y (fx in ref).
    float4 vt, vb, o;
    vt.x = v00.x + (v01.x - v00.x) * fx;
    vt.y = v00.y + (v01.y - v00.y) * fx;
    vt.z = v00.z + (v01.z - v00.z) * fx;
    vt.w = v00.w + (v01.w - v00.w) * fx;
    vb.x = v10.x + (v11.x - v10.x) * fx;
    vb.y = v10.y + (v11.y - v10.y) * fx;
    vb.z = v10.z + (v11.z - v10.z) * fx;
    vb.w = v10.w + (v11.w - v10.w) * fx;
    o.x = vt.x + (vb.x - vt.x) * fy;
    o.y = vt.y + (vb.y - vt.y) * fy;
    o.z = vt.z + (vb.z - vt.z) * fy;
    o.w = vt.w + (vb.w - vt.w) * fy;

    out4[(long long)pix * CVEC + lane_c] = o;
}

extern "C" void kernel_launch(void* const* d_in, const int* in_sizes, int n_in,
                              void* d_out, int out_size, void* d_ws, size_t ws_size,
                              hipStream_t stream) {
    const float*  offsets = (const float*)d_in[0];
    const float4* inputs4 = (const float4*)d_in[1];
    float4*       out4    = (float4*)d_out;

    const int B = in_sizes[0] / (S * S * 2);   // = 16
    const int total_pix = B * S * S;           // 262144
    const int blocks = total_pix / PIX_PER_BLOCK;

    resample_kernel<<<blocks, 256, 0, stream>>>(offsets, inputs4, out4);
}